// Round 2
// baseline (106.530 us; speedup 1.0000x reference)
//
#include <hip/hip_runtime.h>

// Encode 11x11 hex boards -> (B, 27, 12, 12) one-hot pattern tensor.
// Pure store-bandwidth-bound: 509.6 MB output. G boards per block to
// amortize the prologue; output per block is one contiguous 124 KB stream.

#define G 8  // boards per block

typedef float f4 __attribute__((ext_vector_type(4)));

__global__ __launch_bounds__(256) void hex_encode_kernel(
    const float* __restrict__ boards, float* __restrict__ out)
{
    __shared__ float sP[G][169];                           // padded 13x13 boards
    __shared__ __align__(16) unsigned short sMask[G][144]; // per-cell 9-bit masks
    __shared__ unsigned sNeed[27];                         // pattern -> need bits

    const int tid = threadIdx.x;
    const size_t b0 = (size_t)blockIdx.x * G;

    // Pattern LUT: one-hot 3-bit field per pattern component.
    if (tid < 27) {
        int v0 = tid / 9, v1 = (tid / 3) % 3, v2 = tid % 3;
        sNeed[tid] = (1u << v0) | (1u << (3 + v1)) | (1u << (6 + v2));
    }

    // Phase 1: build padded P (13x13) for G boards. 8*169 = 1352 entries.
    // All global loads are independent -> single HBM latency exposure.
    #pragma unroll
    for (int it = 0; it < 6; ++it) {
        int idx = tid + it * 256;
        if (idx < G * 169) {
            int g = idx / 169;
            int pos = idx - g * 169;
            int pr = pos / 13, pc = pos % 13;
            bool ir = (pr >= 1) & (pr <= 11);
            bool jr = (pc >= 1) & (pc <= 11);
            float v;
            if (ir & jr)  v = boards[(b0 + g) * 121 + (pr - 1) * 11 + (pc - 1)];
            else if (jr)  v = 1.0f;    // top/bottom edge rows
            else if (ir)  v = -1.0f;   // left/right edge cols
            else          v = 0.0f;    // corners
            sP[g][pos] = v;
        }
    }
    __syncthreads();

    // Phase 2: per-cell 9-bit match masks (3 fields of 3 bits, one-hot on
    // value+1; corner-override cells get a full 0b111 field). 8*144 = 1152.
    #pragma unroll
    for (int it = 0; it < 5; ++it) {
        int idx = tid + it * 256;
        if (idx < G * 144) {
            int g = idx / 144;
            int cell = idx - g * 144;
            int r = cell / 12, c = cell % 12;
            const float* P = sP[g];
            int i0 = (int)P[r * 13 + c] + 1;        // a0 = P[r][c]
            int i1 = (int)P[r * 13 + c + 1] + 1;    // a1 = P[r][c+1]
            int i2 = (int)P[(r + 1) * 13 + c] + 1;  // a2 = P[r+1][c]
            unsigned m0 = (cell == 0)   ? 7u : (1u << i0);   // eq0 @ (0,0)
            unsigned m1 = (cell == 11)  ? 7u : (1u << i1);   // eq1 @ (0,11)
            unsigned m2 = (cell == 132) ? 7u : (1u << i2);   // eq2 @ (11,0)
            sMask[g][cell] = (unsigned short)(m0 | (m1 << 3) | (m2 << 6));
        }
    }
    __syncthreads();

    // Phase 3: stream 8*972 = 7776 float4 per block, fully contiguous:
    // out_float4[b0*972 + idx]. Nontemporal - never re-read.
    f4* outv = (f4*)out + b0 * 972;
    const unsigned long long* mask64 = (const unsigned long long*)sMask;
    for (int it = 0; it < 31; ++it) {
        int idx = tid + it * 256;
        if (idx < G * 972) {
            int g = idx / 972;
            int rem = idx - g * 972;
            int p = rem / 36;               // pattern 0..26
            int cell4 = rem - p * 36;       // float4 group within 144 cells
            unsigned need = sNeed[p];
            unsigned long long m4 = mask64[g * 36 + cell4];
            f4 o;
            o.x = (((unsigned)(m4)       & need) == need) ? 1.0f : 0.0f;
            o.y = (((unsigned)(m4 >> 16) & need) == need) ? 1.0f : 0.0f;
            o.z = (((unsigned)(m4 >> 32) & need) == need) ? 1.0f : 0.0f;
            o.w = (((unsigned)(m4 >> 48) & need) == need) ? 1.0f : 0.0f;
            __builtin_nontemporal_store(o, &outv[idx]);
        }
    }
}

extern "C" void kernel_launch(void* const* d_in, const int* in_sizes, int n_in,
                              void* d_out, int out_size, void* d_ws, size_t ws_size,
                              hipStream_t stream) {
    const float* boards = (const float*)d_in[0];
    float* out = (float*)d_out;
    hex_encode_kernel<<<32768 / G, 256, 0, stream>>>(boards, out);
}